// Round 1
// baseline (344.138 us; speedup 1.0000x reference)
//
#include <hip/hip_runtime.h>
#include <math.h>

#define N_NODES 100000
#define N_PART  5000
#define N_EDGES 1000000
#define D_NODE  128
#define D_PART  128
#define D_ATT   20
#define NBLK    128   // counting-sort blocks
#define EPB     ((N_EDGES + NBLK - 1) / NBLK)
#define TPV3    10    // particles per block in gru_fused_v3 (5000 = 500*10)

__device__ __forceinline__ float sigmoid_(float x) { return 1.f / (1.f + __expf(-x)); }
__device__ __forceinline__ float tanh_(float x)    { return 1.f - 2.f / (__expf(2.f * x) + 1.f); }

// ---------------------------------------------------------------------------
// P0: build combined GRU weight matrix Wbig[256][512]:
//   rows 0..127  (agg side k):  cols j<384: Wcomb[k][j] = sum_m valW[k][m]*Wih[j][m]
//                               cols j>=384: 0
//   rows 128..255 (h side k'):  cols j<256:  Whh[j][k']      (r and z gates)
//                               cols 256..383: 0
//                               cols 384..511: Whh[j-128][k'] (n gate)
// Column semantics: [0,128)=r (gi+gh), [128,256)=z (gi+gh), [256,384)=i_n, [384,512)=h_n
// ---------------------------------------------------------------------------
__global__ __launch_bounds__(256) void build_wbig_kernel(
    const float* __restrict__ valW, const float* __restrict__ Wih,
    const float* __restrict__ Whh, float* __restrict__ Wbig)
{
    int idx = blockIdx.x * 256 + threadIdx.x;   // 131072 total
    int k = idx >> 9;
    int j = idx & 511;
    float v = 0.f;
    if (k < 128) {
        if (j < 384) {
            float acc = 0.f;
            #pragma unroll 8
            for (int m = 0; m < 128; m++)
                acc += valW[k * 128 + m] * Wih[j * 128 + m];
            v = acc;
        }
    } else {
        int kp = k - 128;
        if (j < 256)       v = Whh[j * 128 + kp];
        else if (j >= 384) v = Whh[(j - 128) * 128 + kp];
    }
    Wbig[k * 512 + j] = v;
}

// P0b: bvec[c] = sum_m valb[m] * Wih[c][m],  c < 384
__global__ __launch_bounds__(256) void build_bvec_kernel(
    const float* __restrict__ valb, const float* __restrict__ Wih,
    float* __restrict__ bvec)
{
    int c = blockIdx.x * 256 + threadIdx.x;
    if (c < 384) {
        float acc = 0.f;
        #pragma unroll 8
        for (int m = 0; m < 128; m++) acc += valb[m] * Wih[c * 128 + m];
        bvec[c] = acc;
    }
}

// ---------------------------------------------------------------------------
// K1: query = [ph|gr] @ q_W + q_b, fold key_W/key_b:
//     qk[p][j] = sum_a key_W[j][a]*query[p][a];  qoff[p] = key_b . query[p]
// ---------------------------------------------------------------------------
__global__ __launch_bounds__(128) void query_qk_kernel(
    const float* __restrict__ ph, const float* __restrict__ gr,
    const float* __restrict__ qW, const float* __restrict__ qb,
    const float* __restrict__ keyW, const float* __restrict__ keyb,
    float* __restrict__ qk, float* __restrict__ qoff)
{
    int p = blockIdx.x;
    int t = threadIdx.x;
    __shared__ float s_in[256];
    __shared__ float s_q[D_ATT];

    s_in[t]       = ph[p * 128 + t];
    s_in[128 + t] = gr[p * 128 + t];
    __syncthreads();

    if (t < D_ATT) {
        float acc = qb[t];
        #pragma unroll 8
        for (int k = 0; k < 256; k++) acc += s_in[k] * qW[k * D_ATT + t];
        s_q[t] = acc;
    }
    __syncthreads();

    float acc = 0.f;
    #pragma unroll
    for (int a = 0; a < D_ATT; a++) acc += keyW[t * D_ATT + a] * s_q[a];
    qk[p * 128 + t] = acc;

    if (t == 0) {
        float o = 0.f;
        #pragma unroll
        for (int a = 0; a < D_ATT; a++) o += keyb[a] * s_q[a];
        qoff[p] = o;
    }
}

// ---------------------------------------------------------------------------
// K2a: per-block LDS histogram of dst
// ---------------------------------------------------------------------------
__global__ __launch_bounds__(256) void block_hist_kernel(
    const int* __restrict__ dst, int* __restrict__ blockhist)
{
    __shared__ int h[N_PART];
    int b = blockIdx.x;
    for (int i = threadIdx.x; i < N_PART; i += 256) h[i] = 0;
    __syncthreads();
    int beg = b * EPB, end = min(beg + EPB, N_EDGES);
    for (int e = beg + threadIdx.x; e < end; e += 256)
        atomicAdd(&h[dst[e]], 1);
    __syncthreads();
    for (int i = threadIdx.x; i < N_PART; i += 256)
        blockhist[(size_t)b * N_PART + i] = h[i];
}

// ---------------------------------------------------------------------------
// K2b: per-dst column scan over blocks
// ---------------------------------------------------------------------------
__global__ __launch_bounds__(256) void colscan_kernel(
    int* __restrict__ blockhist, int* __restrict__ totals)
{
    int i = blockIdx.x * 256 + threadIdx.x;
    if (i >= N_PART) return;
    int run = 0;
    for (int b = 0; b < NBLK; b++) {
        size_t idx = (size_t)b * N_PART + i;
        int v = blockhist[idx];
        blockhist[idx] = run;
        run += v;
    }
    totals[i] = run;
}

// ---------------------------------------------------------------------------
// K2c: exclusive scan of totals[5000] -> offsets[5001]
// ---------------------------------------------------------------------------
__global__ __launch_bounds__(256) void scan_kernel(
    const int* __restrict__ totals, int* __restrict__ offsets)
{
    __shared__ int ss[256];
    int t = threadIdx.x;
    const int CH = 20;
    int beg = t * CH;
    int end = min(beg + CH, N_PART);
    int lsum = 0;
    for (int i = beg; i < end; i++) lsum += totals[i];
    ss[t] = lsum;
    __syncthreads();
    for (int off = 1; off < 256; off <<= 1) {
        int v = (t >= off) ? ss[t - off] : 0;
        __syncthreads();
        ss[t] += v;
        __syncthreads();
    }
    int base = ss[t] - lsum;
    for (int i = beg; i < end; i++) {
        offsets[i] = base;
        base += totals[i];
    }
    if (t == 0) offsets[N_PART] = N_EDGES;
}

// ---------------------------------------------------------------------------
// K2d: scatter src into dst-sorted order using per-block LDS cursors
// ---------------------------------------------------------------------------
__global__ __launch_bounds__(256) void scatter_sorted_kernel(
    const int* __restrict__ src, const int* __restrict__ dst,
    const int* __restrict__ offsets, const int* __restrict__ blockhist,
    int* __restrict__ ssrc)
{
    __shared__ int cur[N_PART];
    int b = blockIdx.x;
    for (int i = threadIdx.x; i < N_PART; i += 256)
        cur[i] = offsets[i] + blockhist[(size_t)b * N_PART + i];
    __syncthreads();
    int beg = b * EPB, end = min(beg + EPB, N_EDGES);
    for (int e = beg + threadIdx.x; e < end; e += 256) {
        int d = dst[e];
        int pos = atomicAdd(&cur[d], 1);
        ssrc[pos] = src[e];
    }
}

// ---------------------------------------------------------------------------
// K3: per-dst edge accumulation. Half-wave (32 lanes x float4) per edge.
// v2: 8 pairs (16 edges) in flight per wave per iteration + index prefetch.
// Latency-bound gather: double the outstanding 512B loads per wave and hide
// the ssrc->nodes dependent-load chain under the previous group's reduce.
// ---------------------------------------------------------------------------
__global__ __launch_bounds__(256) void edge_agg_kernel(
    const float* __restrict__ nodes, const float* __restrict__ qk,
    const float* __restrict__ qoff,
    const int* __restrict__ offsets, const int* __restrict__ ssrc,
    float* __restrict__ agg, float* __restrict__ att_sum)
{
    const float norm = 0.22360679774997896f;  // 1/sqrt(20)
    int p = blockIdx.x;
    int tid = threadIdx.x;
    int lane = tid & 63;
    int wave = tid >> 6;
    int half = lane >> 5;
    int colq = (lane & 31) * 4;

    const float4 q = *(const float4*)(qk + (size_t)p * 128 + colq);
    float qo = qoff[p];
    int beg = offsets[p], end = offsets[p + 1];
    int n = end - beg;
    int np = (n + 1) >> 1;   // total pairs (last may be partial)
    int npfull = n >> 1;     // pairs with both edges present

    float4 a = {0.f, 0.f, 0.f, 0.f};
    float asum = 0.f;

    int pi = wave;
    // prefetch first group's indices: pairs pi+4j (j=0..7), edge = beg+2*(pi+4j)+half
    int sidx[8];
    bool have = (pi + 28 < npfull);
    if (have) {
        int e0 = beg + 2 * pi + half;
        #pragma unroll
        for (int j = 0; j < 8; j++) sidx[j] = ssrc[e0 + 8 * j];
    }
    while (have) {
        // issue 8 x 512B gathers (per half-wave)
        float4 x[8];
        #pragma unroll
        for (int j = 0; j < 8; j++)
            x[j] = *(const float4*)(nodes + (size_t)sidx[j] * 128 + colq);

        // prefetch next group's indices while gathers are in flight
        int pin = pi + 32;
        bool haven = (pin + 28 < npfull);
        if (haven) {
            int e0 = beg + 2 * pin + half;
            #pragma unroll
            for (int j = 0; j < 8; j++) sidx[j] = ssrc[e0 + 8 * j];
        }

        // per-lane partial dots
        float d[8];
        #pragma unroll
        for (int j = 0; j < 8; j++)
            d[j] = x[j].x * q.x + x[j].y * q.y + x[j].z * q.z + x[j].w * q.w;

        // 32-lane butterfly reduce (offsets <=16 stay within half-wave)
        #pragma unroll
        for (int off = 1; off <= 16; off <<= 1) {
            #pragma unroll
            for (int j = 0; j < 8; j++) d[j] += __shfl_xor(d[j], off, 64);
        }

        #pragma unroll
        for (int j = 0; j < 8; j++) {
            float t = (d[j] + qo) * norm;
            a.x += t * x[j].x; a.y += t * x[j].y;
            a.z += t * x[j].z; a.w += t * x[j].w;
            asum += t;
        }
        pi = pin; have = haven;
    }
    // remainder: guarded single pairs
    for (; pi < np; pi += 4) {
        int e0 = beg + 2 * pi;
        bool has1 = (e0 + 1 < end);
        int s0 = ssrc[e0];
        int s1 = has1 ? ssrc[e0 + 1] : s0;
        int s = half ? s1 : s0;
        float4 x = *(const float4*)(nodes + (size_t)s * 128 + colq);
        float d = x.x * q.x + x.y * q.y + x.z * q.z + x.w * q.w;
        #pragma unroll
        for (int off = 1; off <= 16; off <<= 1) d += __shfl_xor(d, off, 64);
        float att = (d + qo) * norm;
        if (half && !has1) att = 0.f;
        a.x += att * x.x; a.y += att * x.y; a.z += att * x.z; a.w += att * x.w;
        asum += att;
    }

    a.x += __shfl_xor(a.x, 32, 64);
    a.y += __shfl_xor(a.y, 32, 64);
    a.z += __shfl_xor(a.z, 32, 64);
    a.w += __shfl_xor(a.w, 32, 64);
    asum += __shfl_xor(asum, 32, 64);

    __shared__ float s_acc[4][128];
    __shared__ float s_as[4];
    if (lane < 32) {
        *(float4*)&s_acc[wave][colq] = a;
        if (lane == 0) s_as[wave] = asum;
    }
    __syncthreads();

    if (tid < 128) {
        float v = s_acc[0][tid] + s_acc[1][tid] + s_acc[2][tid] + s_acc[3][tid];
        agg[(size_t)p * 128 + tid] = v;
        if (tid == 0) att_sum[p] = s_as[0] + s_as[1] + s_as[2] + s_as[3];
    }
}

// ---------------------------------------------------------------------------
// K4 v3: single K=256 GEMM  G = [agg|h] @ Wbig  (+bias/asum*bvec),
// then gates + LayerNorm + MLP + residual, all in one kernel.
// 256 threads, 10 particles/block, 500 blocks.
// v3.1: K-loop unrolled by 4 with float4 s_in reads — cuts DS ops from
// (256 b128 + 1280 b32) to 576 b128 per thread (DS pipe was critical path).
// ---------------------------------------------------------------------------
__global__ __launch_bounds__(256) void gru_fused_v3(
    const float* __restrict__ agg, const float* __restrict__ att_sum,
    const float* __restrict__ ph,
    const float* __restrict__ Wbig, const float* __restrict__ bvec,
    const float* __restrict__ bih, const float* __restrict__ bhh,
    const float* __restrict__ lng, const float* __restrict__ lnb,
    const float* __restrict__ W1, const float* __restrict__ b1,
    const float* __restrict__ W2, const float* __restrict__ b2,
    float* __restrict__ out)
{
    __shared__ float s_in[TPV3][256];    // [agg | h] per particle
    __shared__ float s_w[16][512];       // weight chunk
    __shared__ float s_acc[TPV3][512];   // GEMM outputs
    __shared__ float s_ln[TPV3][128];
    __shared__ float s_hid[TPV3][64];

    int t = threadIdx.x;
    int pbase = blockIdx.x * TPV3;

    // ---- load inputs: 10 particles x 256 floats = 640 float4 jobs
    for (int f = t; f < TPV3 * 64; f += 256) {
        int pl = f >> 6, r = f & 63;
        int c4 = r * 4;
        int p = pbase + pl;
        float4 v;
        if (c4 < 128) v = *(const float4*)(agg + (size_t)p * 128 + c4);
        else          v = *(const float4*)(ph + (size_t)p * 128 + (c4 - 128));
        *(float4*)&s_in[pl][c4] = v;
    }

    // ---- accumulator init: bias + asum * bvec
    int jq = t & 127;        // column quad 0..127
    int j4 = jq * 4;         // absolute column 0..508
    int pg = t >> 7;         // particle group 0/1 -> particles pg*5 .. pg*5+4
    float4 cb, bv;
    if (j4 < 256) {          // r, z: bih + bhh, bvec active
        float4 bi = *(const float4*)(bih + j4);
        float4 bh = *(const float4*)(bhh + j4);
        cb.x = bi.x + bh.x; cb.y = bi.y + bh.y; cb.z = bi.z + bh.z; cb.w = bi.w + bh.w;
        bv = *(const float4*)(bvec + j4);
    } else if (j4 < 384) {   // i_n: bih only, bvec active
        cb = *(const float4*)(bih + j4);
        bv = *(const float4*)(bvec + j4);
    } else {                 // h_n: bhh[j4-128], no bvec
        cb = *(const float4*)(bhh + (j4 - 128));
        bv.x = bv.y = bv.z = bv.w = 0.f;
    }
    float4 acc[5];
    #pragma unroll
    for (int i = 0; i < 5; i++) {
        float as = att_sum[pbase + pg * 5 + i];
        acc[i].x = cb.x + as * bv.x;
        acc[i].y = cb.y + as * bv.y;
        acc[i].z = cb.z + as * bv.z;
        acc[i].w = cb.w + as * bv.w;
    }
    __syncthreads();

    // ---- K-loop: 16 chunks of 16 rows
    for (int kc = 0; kc < 16; kc++) {
        int k0 = kc * 16;
        // stage chunk: 16*512 floats = 2048 float4s, 8 per thread
        #pragma unroll
        for (int f = 0; f < 8; f++) {
            int idx = t + f * 256;          // float4 index
            int row = idx >> 7;
            int c4 = (idx & 127) * 4;
            *(float4*)&s_w[row][c4] = *(const float4*)(Wbig + (size_t)(k0 + row) * 512 + c4);
        }
        __syncthreads();
        #pragma unroll
        for (int kk = 0; kk < 16; kk += 4) {
            float4 w0 = *(const float4*)&s_w[kk    ][j4];
            float4 w1 = *(const float4*)&s_w[kk + 1][j4];
            float4 w2 = *(const float4*)&s_w[kk + 2][j4];
            float4 w3 = *(const float4*)&s_w[kk + 3][j4];
            #pragma unroll
            for (int i = 0; i < 5; i++) {
                float4 xi = *(const float4*)&s_in[pg * 5 + i][k0 + kk];
                acc[i].x += xi.x * w0.x + xi.y * w1.x + xi.z * w2.x + xi.w * w3.x;
                acc[i].y += xi.x * w0.y + xi.y * w1.y + xi.z * w2.y + xi.w * w3.y;
                acc[i].z += xi.x * w0.z + xi.y * w1.z + xi.z * w2.z + xi.w * w3.z;
                acc[i].w += xi.x * w0.w + xi.y * w1.w + xi.z * w2.w + xi.w * w3.w;
            }
        }
        __syncthreads();
    }

    // ---- dump accumulators to LDS
    #pragma unroll
    for (int i = 0; i < 5; i++)
        *(float4*)&s_acc[pg * 5 + i][j4] = acc[i];
    __syncthreads();

    // ---- gates: hn = (1-z)*n + z*h   (320 column-quads)
    for (int idx = t; idx < TPV3 * 32; idx += 256) {
        int pl = idx >> 5, qd = idx & 31;
        int c4 = qd * 4;
        float4 r4 = *(const float4*)&s_acc[pl][c4];
        float4 z4 = *(const float4*)&s_acc[pl][128 + c4];
        float4 i4 = *(const float4*)&s_acc[pl][256 + c4];
        float4 n4 = *(const float4*)&s_acc[pl][384 + c4];
        float4 h4 = *(const float4*)&s_in[pl][128 + c4];
        float r0 = sigmoid_(r4.x), r1 = sigmoid_(r4.y), r2 = sigmoid_(r4.z), r3 = sigmoid_(r4.w);
        float z0 = sigmoid_(z4.x), z1 = sigmoid_(z4.y), z2 = sigmoid_(z4.z), z3 = sigmoid_(z4.w);
        float n0 = tanh_(i4.x + r0 * n4.x), n1 = tanh_(i4.y + r1 * n4.y);
        float n2 = tanh_(i4.z + r2 * n4.z), n3 = tanh_(i4.w + r3 * n4.w);
        float4 hn;
        hn.x = (1.f - z0) * n0 + z0 * h4.x;
        hn.y = (1.f - z1) * n1 + z1 * h4.y;
        hn.z = (1.f - z2) * n2 + z2 * h4.z;
        hn.w = (1.f - z3) * n3 + z3 * h4.w;
        *(float4*)&s_ln[pl][c4] = hn;
    }
    __syncthreads();

    // ---- LayerNorm per particle (wave w handles particles w, w+4, w+8)
    {
        int wv = t >> 6, l = t & 63;
        for (int pl = wv; pl < TPV3; pl += 4) {
            float v0 = s_ln[pl][l * 2], v1 = s_ln[pl][l * 2 + 1];
            float sum = v0 + v1, sq = v0 * v0 + v1 * v1;
            #pragma unroll
            for (int off = 1; off <= 32; off <<= 1) {
                sum += __shfl_xor(sum, off, 64);
                sq  += __shfl_xor(sq, off, 64);
            }
            float mu = sum * (1.f / 128.f);
            float var = sq * (1.f / 128.f) - mu * mu;
            float rstd = rsqrtf(var + 1e-5f);
            s_ln[pl][l * 2]     = (v0 - mu) * rstd * lng[l * 2] + lnb[l * 2];
            s_ln[pl][l * 2 + 1] = (v1 - mu) * rstd * lng[l * 2 + 1] + lnb[l * 2 + 1];
        }
    }
    __syncthreads();

    // ---- MLP hidden (10*64 = 640 outputs)
    for (int idx = t; idx < TPV3 * 64; idx += 256) {
        int pl = idx >> 6, u = idx & 63;
        float a0 = b1[u];
        #pragma unroll 4
        for (int k = 0; k < 128; k++) a0 += s_ln[pl][k] * W1[k * 64 + u];
        s_hid[pl][u] = fmaxf(a0, 0.f);
    }
    __syncthreads();

    // ---- MLP out + residual (320 column-quads)
    for (int idx = t; idx < TPV3 * 32; idx += 256) {
        int pl = idx >> 5, qd = idx & 31;
        int c4 = qd * 4;
        float4 o = *(const float4*)(b2 + c4);
        #pragma unroll 4
        for (int u = 0; u < 64; u++) {
            float av = s_hid[pl][u];
            float4 w = *(const float4*)(W2 + u * 128 + c4);
            o.x += av * w.x; o.y += av * w.y; o.z += av * w.z; o.w += av * w.w;
        }
        float4 h4 = *(const float4*)&s_in[pl][128 + c4];
        float4 res;
        res.x = h4.x + o.x; res.y = h4.y + o.y;
        res.z = h4.z + o.z; res.w = h4.w + o.w;
        *(float4*)(out + (size_t)(pbase + pl) * 128 + c4) = res;
    }
}

// ---------------------------------------------------------------------------
extern "C" void kernel_launch(void* const* d_in, const int* in_sizes, int n_in,
                              void* d_out, int out_size, void* d_ws, size_t ws_size,
                              hipStream_t stream) {
    const float* nodes = (const float*)d_in[0];
    const float* ph    = (const float*)d_in[1];
    const float* gr    = (const float*)d_in[2];
    const int*   src   = (const int*)d_in[3];
    const int*   dst   = (const int*)d_in[4];
    const float* keyW  = (const float*)d_in[5];
    const float* keyb  = (const float*)d_in[6];
    const float* valW  = (const float*)d_in[7];
    const float* valb  = (const float*)d_in[8];
    const float* qW    = (const float*)d_in[9];
    const float* qb    = (const float*)d_in[10];
    const float* Wih   = (const float*)d_in[11];
    const float* Whh   = (const float*)d_in[12];
    const float* bih   = (const float*)d_in[13];
    const float* bhh   = (const float*)d_in[14];
    const float* lng   = (const float*)d_in[15];
    const float* lnb   = (const float*)d_in[16];
    const float* W1    = (const float*)d_in[17];
    const float* b1    = (const float*)d_in[18];
    const float* W2    = (const float*)d_in[19];
    const float* b2    = (const float*)d_in[20];
    float* out = (float*)d_out;

    // workspace layout
    float* ws_f      = (float*)d_ws;
    float* qk        = ws_f;                     // 640,000
    float* qoff      = qk + 640000;              // 5,008
    float* agg       = qoff + 5008;              // 640,000
    float* att_sum   = agg + 640000;             // 5,008
    int*   totals    = (int*)(att_sum + 5008);   // 5,008
    int*   offsets   = totals + 5008;            // 5,008
    int*   blockhist = offsets + 5008;           // NBLK*5000
    int*   ssrc      = blockhist + (size_t)NBLK * N_PART;  // 1,000,000
    float* Wbig      = (float*)(ssrc + 1000000); // 131,072
    float* bvec      = Wbig + 131072;            // 384 (+pad)

    build_wbig_kernel<<<512, 256, 0, stream>>>(valW, Wih, Whh, Wbig);
    build_bvec_kernel<<<2, 256, 0, stream>>>(valb, Wih, bvec);
    query_qk_kernel<<<N_PART, 128, 0, stream>>>(ph, gr, qW, qb, keyW, keyb, qk, qoff);
    block_hist_kernel<<<NBLK, 256, 0, stream>>>(dst, blockhist);
    colscan_kernel<<<(N_PART + 255) / 256, 256, 0, stream>>>(blockhist, totals);
    scan_kernel<<<1, 256, 0, stream>>>(totals, offsets);
    scatter_sorted_kernel<<<NBLK, 256, 0, stream>>>(src, dst, offsets, blockhist, ssrc);
    edge_agg_kernel<<<N_PART, 256, 0, stream>>>(nodes, qk, qoff, offsets, ssrc, agg, att_sum);
    gru_fused_v3<<<N_PART / TPV3, 256, 0, stream>>>(
        agg, att_sum, ph, Wbig, bvec, bih, bhh, lng, lnb, W1, b1, W2, b2, out);
}

// Round 2
// 334.307 us; speedup vs baseline: 1.0294x; 1.0294x over previous
//
#include <hip/hip_runtime.h>
#include <math.h>

#define N_NODES 100000
#define N_PART  5000
#define N_EDGES 1000000
#define D_NODE  128
#define D_PART  128
#define D_ATT   20
#define NBLK    128   // counting-sort blocks
#define EPB     ((N_EDGES + NBLK - 1) / NBLK)
#define TPV3    10    // particles per block in gru_fused_v4 (5000 = 500*10)

__device__ __forceinline__ float sigmoid_(float x) { return 1.f / (1.f + __expf(-x)); }
__device__ __forceinline__ float tanh_(float x)    { return 1.f - 2.f / (__expf(2.f * x) + 1.f); }

// ---------------------------------------------------------------------------
// P0: build combined GRU weight matrix Wbig[256][512], GATE-INTERLEAVED:
//   new column jn = c*4 + g  (c in [0,128), g in {0:r, 1:z, 2:i_n, 3:h_n})
//   maps to old column j = g*128 + c with old semantics:
//   rows 0..127  (agg side k):  old j<384: sum_m valW[k][m]*Wih[j][m]; else 0
//   rows 128..255 (h side k'):  old j<256: Whh[j][k']; 256..383: 0;
//                               >=384: Whh[j-128][k']
// ---------------------------------------------------------------------------
__global__ __launch_bounds__(256) void build_wbig_kernel(
    const float* __restrict__ valW, const float* __restrict__ Wih,
    const float* __restrict__ Whh, float* __restrict__ Wbig)
{
    int idx = blockIdx.x * 256 + threadIdx.x;   // 131072 total
    int k = idx >> 9;
    int jn = idx & 511;
    int j = (jn & 3) * 128 + (jn >> 2);         // old column
    float v = 0.f;
    if (k < 128) {
        if (j < 384) {
            float acc = 0.f;
            #pragma unroll 8
            for (int m = 0; m < 128; m++)
                acc += valW[k * 128 + m] * Wih[j * 128 + m];
            v = acc;
        }
    } else {
        int kp = k - 128;
        if (j < 256)       v = Whh[j * 128 + kp];
        else if (j >= 384) v = Whh[(j - 128) * 128 + kp];
    }
    Wbig[k * 512 + jn] = v;
}

// P0b: bvec[c] = sum_m valb[m] * Wih[c][m],  c < 384  (old column indexing)
__global__ __launch_bounds__(256) void build_bvec_kernel(
    const float* __restrict__ valb, const float* __restrict__ Wih,
    float* __restrict__ bvec)
{
    int c = blockIdx.x * 256 + threadIdx.x;
    if (c < 384) {
        float acc = 0.f;
        #pragma unroll 8
        for (int m = 0; m < 128; m++) acc += valb[m] * Wih[c * 128 + m];
        bvec[c] = acc;
    }
}

// ---------------------------------------------------------------------------
// K1: query = [ph|gr] @ q_W + q_b, fold key_W/key_b:
//     qk[p][j] = sum_a key_W[j][a]*query[p][a];  qoff[p] = key_b . query[p]
// ---------------------------------------------------------------------------
__global__ __launch_bounds__(128) void query_qk_kernel(
    const float* __restrict__ ph, const float* __restrict__ gr,
    const float* __restrict__ qW, const float* __restrict__ qb,
    const float* __restrict__ keyW, const float* __restrict__ keyb,
    float* __restrict__ qk, float* __restrict__ qoff)
{
    int p = blockIdx.x;
    int t = threadIdx.x;
    __shared__ float s_in[256];
    __shared__ float s_q[D_ATT];

    s_in[t]       = ph[p * 128 + t];
    s_in[128 + t] = gr[p * 128 + t];
    __syncthreads();

    if (t < D_ATT) {
        float acc = qb[t];
        #pragma unroll 8
        for (int k = 0; k < 256; k++) acc += s_in[k] * qW[k * D_ATT + t];
        s_q[t] = acc;
    }
    __syncthreads();

    float acc = 0.f;
    #pragma unroll
    for (int a = 0; a < D_ATT; a++) acc += keyW[t * D_ATT + a] * s_q[a];
    qk[p * 128 + t] = acc;

    if (t == 0) {
        float o = 0.f;
        #pragma unroll
        for (int a = 0; a < D_ATT; a++) o += keyb[a] * s_q[a];
        qoff[p] = o;
    }
}

// ---------------------------------------------------------------------------
// K2a: per-block LDS histogram of dst
// ---------------------------------------------------------------------------
__global__ __launch_bounds__(256) void block_hist_kernel(
    const int* __restrict__ dst, int* __restrict__ blockhist)
{
    __shared__ int h[N_PART];
    int b = blockIdx.x;
    for (int i = threadIdx.x; i < N_PART; i += 256) h[i] = 0;
    __syncthreads();
    int beg = b * EPB, end = min(beg + EPB, N_EDGES);
    for (int e = beg + threadIdx.x; e < end; e += 256)
        atomicAdd(&h[dst[e]], 1);
    __syncthreads();
    for (int i = threadIdx.x; i < N_PART; i += 256)
        blockhist[(size_t)b * N_PART + i] = h[i];
}

// ---------------------------------------------------------------------------
// K2b: per-dst column scan over blocks
// ---------------------------------------------------------------------------
__global__ __launch_bounds__(256) void colscan_kernel(
    int* __restrict__ blockhist, int* __restrict__ totals)
{
    int i = blockIdx.x * 256 + threadIdx.x;
    if (i >= N_PART) return;
    int run = 0;
    for (int b = 0; b < NBLK; b++) {
        size_t idx = (size_t)b * N_PART + i;
        int v = blockhist[idx];
        blockhist[idx] = run;
        run += v;
    }
    totals[i] = run;
}

// ---------------------------------------------------------------------------
// K2c: exclusive scan of totals[5000] -> offsets[5001]
// ---------------------------------------------------------------------------
__global__ __launch_bounds__(256) void scan_kernel(
    const int* __restrict__ totals, int* __restrict__ offsets)
{
    __shared__ int ss[256];
    int t = threadIdx.x;
    const int CH = 20;
    int beg = t * CH;
    int end = min(beg + CH, N_PART);
    int lsum = 0;
    for (int i = beg; i < end; i++) lsum += totals[i];
    ss[t] = lsum;
    __syncthreads();
    for (int off = 1; off < 256; off <<= 1) {
        int v = (t >= off) ? ss[t - off] : 0;
        __syncthreads();
        ss[t] += v;
        __syncthreads();
    }
    int base = ss[t] - lsum;
    for (int i = beg; i < end; i++) {
        offsets[i] = base;
        base += totals[i];
    }
    if (t == 0) offsets[N_PART] = N_EDGES;
}

// ---------------------------------------------------------------------------
// K2d: scatter src into dst-sorted order using per-block LDS cursors
// ---------------------------------------------------------------------------
__global__ __launch_bounds__(256) void scatter_sorted_kernel(
    const int* __restrict__ src, const int* __restrict__ dst,
    const int* __restrict__ offsets, const int* __restrict__ blockhist,
    int* __restrict__ ssrc)
{
    __shared__ int cur[N_PART];
    int b = blockIdx.x;
    for (int i = threadIdx.x; i < N_PART; i += 256)
        cur[i] = offsets[i] + blockhist[(size_t)b * N_PART + i];
    __syncthreads();
    int beg = b * EPB, end = min(beg + EPB, N_EDGES);
    for (int e = beg + threadIdx.x; e < end; e += 256) {
        int d = dst[e];
        int pos = atomicAdd(&cur[d], 1);
        ssrc[pos] = src[e];
    }
}

// ---------------------------------------------------------------------------
// K3: per-dst edge accumulation. Half-wave (32 lanes x float4) per edge.
// Round-0 form (known-good): 4 pairs (8 edges) in flight per wave per iter.
// ---------------------------------------------------------------------------
__global__ __launch_bounds__(256) void edge_agg_kernel(
    const float* __restrict__ nodes, const float* __restrict__ qk,
    const float* __restrict__ qoff,
    const int* __restrict__ offsets, const int* __restrict__ ssrc,
    float* __restrict__ agg, float* __restrict__ att_sum)
{
    const float norm = 0.22360679774997896f;  // 1/sqrt(20)
    int p = blockIdx.x;
    int tid = threadIdx.x;
    int lane = tid & 63;
    int wave = tid >> 6;
    int half = lane >> 5;
    int colq = (lane & 31) * 4;

    const float4 q = *(const float4*)(qk + (size_t)p * 128 + colq);
    float qo = qoff[p];
    int beg = offsets[p], end = offsets[p + 1];
    int n = end - beg;
    int np = (n + 1) >> 1;   // total pairs (last may be partial)
    int npfull = n >> 1;     // pairs with both edges present

    float4 a = {0.f, 0.f, 0.f, 0.f};
    float asum = 0.f;

    int pi = wave;
    // main loop: 4 full pairs pi, pi+4, pi+8, pi+12
    for (; pi + 12 < npfull; pi += 16) {
        int e0 = beg + 2 * pi + half;
        int s0 = ssrc[e0];
        int s1 = ssrc[e0 + 8];
        int s2 = ssrc[e0 + 16];
        int s3 = ssrc[e0 + 24];
        float4 x0 = *(const float4*)(nodes + (size_t)s0 * 128 + colq);
        float4 x1 = *(const float4*)(nodes + (size_t)s1 * 128 + colq);
        float4 x2 = *(const float4*)(nodes + (size_t)s2 * 128 + colq);
        float4 x3 = *(const float4*)(nodes + (size_t)s3 * 128 + colq);
        float d0 = x0.x * q.x + x0.y * q.y + x0.z * q.z + x0.w * q.w;
        float d1 = x1.x * q.x + x1.y * q.y + x1.z * q.z + x1.w * q.w;
        float d2 = x2.x * q.x + x2.y * q.y + x2.z * q.z + x2.w * q.w;
        float d3 = x3.x * q.x + x3.y * q.y + x3.z * q.z + x3.w * q.w;
        #pragma unroll
        for (int off = 1; off <= 16; off <<= 1) {
            d0 += __shfl_xor(d0, off, 64);
            d1 += __shfl_xor(d1, off, 64);
            d2 += __shfl_xor(d2, off, 64);
            d3 += __shfl_xor(d3, off, 64);
        }
        float t0 = (d0 + qo) * norm;
        float t1 = (d1 + qo) * norm;
        float t2 = (d2 + qo) * norm;
        float t3 = (d3 + qo) * norm;
        a.x += t0 * x0.x + t1 * x1.x + t2 * x2.x + t3 * x3.x;
        a.y += t0 * x0.y + t1 * x1.y + t2 * x2.y + t3 * x3.y;
        a.z += t0 * x0.z + t1 * x1.z + t2 * x2.z + t3 * x3.z;
        a.w += t0 * x0.w + t1 * x1.w + t2 * x2.w + t3 * x3.w;
        asum += t0 + t1 + t2 + t3;
    }
    // remainder: guarded single pairs
    for (; pi < np; pi += 4) {
        int e0 = beg + 2 * pi;
        bool has1 = (e0 + 1 < end);
        int s0 = ssrc[e0];
        int s1 = has1 ? ssrc[e0 + 1] : s0;
        int s = half ? s1 : s0;
        float4 x = *(const float4*)(nodes + (size_t)s * 128 + colq);
        float d = x.x * q.x + x.y * q.y + x.z * q.z + x.w * q.w;
        #pragma unroll
        for (int off = 1; off <= 16; off <<= 1) d += __shfl_xor(d, off, 64);
        float att = (d + qo) * norm;
        if (half && !has1) att = 0.f;
        a.x += att * x.x; a.y += att * x.y; a.z += att * x.z; a.w += att * x.w;
        asum += att;
    }

    a.x += __shfl_xor(a.x, 32, 64);
    a.y += __shfl_xor(a.y, 32, 64);
    a.z += __shfl_xor(a.z, 32, 64);
    a.w += __shfl_xor(a.w, 32, 64);
    asum += __shfl_xor(asum, 32, 64);

    __shared__ float s_acc[4][128];
    __shared__ float s_as[4];
    if (lane < 32) {
        *(float4*)&s_acc[wave][colq] = a;
        if (lane == 0) s_as[wave] = asum;
    }
    __syncthreads();

    if (tid < 128) {
        float v = s_acc[0][tid] + s_acc[1][tid] + s_acc[2][tid] + s_acc[3][tid];
        agg[(size_t)p * 128 + tid] = v;
        if (tid == 0) att_sum[p] = s_as[0] + s_as[1] + s_as[2] + s_as[3];
    }
}

// ---------------------------------------------------------------------------
// K4 v4: single K=256 GEMM  G = [agg|h] @ Wbig_interleaved (+bias/asum*bvec),
// then gates IN REGISTERS + LayerNorm + MLP + residual, all in one kernel.
// 256 threads, 10 particles/block, 500 blocks.
// Thread t owns output column c = t&127 for particles pg*5..pg*5+4 (pg=t>>7);
// acc[i] = float4 of (r,z,i_n,h_n) pre-activations -> gates need no LDS
// redistribution. s_acc (20KB) deleted: LDS 71168 -> 50688 B = 3 blocks/CU.
// K-loop instruction mix identical to the measured-fastest round-0 version.
// ---------------------------------------------------------------------------
__global__ __launch_bounds__(256) void gru_fused_v4(
    const float* __restrict__ agg, const float* __restrict__ att_sum,
    const float* __restrict__ ph,
    const float* __restrict__ Wbig, const float* __restrict__ bvec,
    const float* __restrict__ bih, const float* __restrict__ bhh,
    const float* __restrict__ lng, const float* __restrict__ lnb,
    const float* __restrict__ W1, const float* __restrict__ b1,
    const float* __restrict__ W2, const float* __restrict__ b2,
    float* __restrict__ out)
{
    __shared__ float s_in[TPV3][256];    // [agg | h] per particle (10240 B)
    __shared__ float s_w[16][512];       // weight chunk          (32768 B)
    __shared__ float s_ln[TPV3][128];    //                        (5120 B)
    __shared__ float s_hid[TPV3][64];    //                        (2560 B)

    int t = threadIdx.x;
    int pbase = blockIdx.x * TPV3;

    // ---- load inputs: 10 particles x 256 floats = 640 float4 jobs
    for (int f = t; f < TPV3 * 64; f += 256) {
        int pl = f >> 6, r = f & 63;
        int c4 = r * 4;
        int p = pbase + pl;
        float4 v;
        if (c4 < 128) v = *(const float4*)(agg + (size_t)p * 128 + c4);
        else          v = *(const float4*)(ph + (size_t)p * 128 + (c4 - 128));
        *(float4*)&s_in[pl][c4] = v;
    }

    // ---- accumulator init: bias + asum * bvec (gate-interleaved)
    int c  = t & 127;        // output column 0..127
    int j4 = c * 4;          // interleaved column base in Wbig
    int pg = t >> 7;         // particle group 0/1 -> particles pg*5 .. pg*5+4
    float4 cb, bv;
    cb.x = bih[c]       + bhh[c];        bv.x = bvec[c];        // r
    cb.y = bih[128 + c] + bhh[128 + c];  bv.y = bvec[128 + c];  // z
    cb.z = bih[256 + c];                 bv.z = bvec[256 + c];  // i_n
    cb.w = bhh[256 + c];                 bv.w = 0.f;            // h_n
    float4 acc[5];
    #pragma unroll
    for (int i = 0; i < 5; i++) {
        float as = att_sum[pbase + pg * 5 + i];
        acc[i].x = cb.x + as * bv.x;
        acc[i].y = cb.y + as * bv.y;
        acc[i].z = cb.z + as * bv.z;
        acc[i].w = cb.w + as * bv.w;
    }
    __syncthreads();

    // ---- K-loop: 16 chunks of 16 rows (round-0 instruction mix)
    for (int kc = 0; kc < 16; kc++) {
        int k0 = kc * 16;
        // stage chunk: 16*512 floats = 2048 float4s, 8 per thread
        #pragma unroll
        for (int f = 0; f < 8; f++) {
            int idx = t + f * 256;          // float4 index
            int row = idx >> 7;
            int c4 = (idx & 127) * 4;
            *(float4*)&s_w[row][c4] = *(const float4*)(Wbig + (size_t)(k0 + row) * 512 + c4);
        }
        __syncthreads();
        #pragma unroll
        for (int kk = 0; kk < 16; kk++) {
            int k = k0 + kk;
            float4 w = *(const float4*)&s_w[kk][j4];
            #pragma unroll
            for (int i = 0; i < 5; i++) {
                float x = s_in[pg * 5 + i][k];
                acc[i].x += x * w.x; acc[i].y += x * w.y;
                acc[i].z += x * w.z; acc[i].w += x * w.w;
            }
        }
        __syncthreads();
    }

    // ---- gates entirely in registers: hn = (1-z)*n + z*h
    #pragma unroll
    for (int i = 0; i < 5; i++) {
        int pl = pg * 5 + i;
        float r = sigmoid_(acc[i].x);
        float z = sigmoid_(acc[i].y);
        float n = tanh_(acc[i].z + r * acc[i].w);
        float h = s_in[pl][128 + c];
        s_ln[pl][c] = (1.f - z) * n + z * h;
    }
    __syncthreads();

    // ---- LayerNorm per particle (wave w handles particles w, w+4, w+8)
    {
        int wv = t >> 6, l = t & 63;
        for (int pl = wv; pl < TPV3; pl += 4) {
            float v0 = s_ln[pl][l * 2], v1 = s_ln[pl][l * 2 + 1];
            float sum = v0 + v1, sq = v0 * v0 + v1 * v1;
            #pragma unroll
            for (int off = 1; off <= 32; off <<= 1) {
                sum += __shfl_xor(sum, off, 64);
                sq  += __shfl_xor(sq, off, 64);
            }
            float mu = sum * (1.f / 128.f);
            float var = sq * (1.f / 128.f) - mu * mu;
            float rstd = rsqrtf(var + 1e-5f);
            s_ln[pl][l * 2]     = (v0 - mu) * rstd * lng[l * 2] + lnb[l * 2];
            s_ln[pl][l * 2 + 1] = (v1 - mu) * rstd * lng[l * 2 + 1] + lnb[l * 2 + 1];
        }
    }
    __syncthreads();

    // ---- MLP hidden (10*64 = 640 outputs)
    for (int idx = t; idx < TPV3 * 64; idx += 256) {
        int pl = idx >> 6, u = idx & 63;
        float a0 = b1[u];
        #pragma unroll 4
        for (int k = 0; k < 128; k++) a0 += s_ln[pl][k] * W1[k * 64 + u];
        s_hid[pl][u] = fmaxf(a0, 0.f);
    }
    __syncthreads();

    // ---- MLP out + residual (320 column-quads)
    for (int idx = t; idx < TPV3 * 32; idx += 256) {
        int pl = idx >> 5, qd = idx & 31;
        int c4 = qd * 4;
        float4 o = *(const float4*)(b2 + c4);
        #pragma unroll 4
        for (int u = 0; u < 64; u++) {
            float av = s_hid[pl][u];
            float4 w = *(const float4*)(W2 + u * 128 + c4);
            o.x += av * w.x; o.y += av * w.y; o.z += av * w.z; o.w += av * w.w;
        }
        float4 h4 = *(const float4*)&s_in[pl][128 + c4];
        float4 res;
        res.x = h4.x + o.x; res.y = h4.y + o.y;
        res.z = h4.z + o.z; res.w = h4.w + o.w;
        *(float4*)(out + (size_t)(pbase + pl) * 128 + c4) = res;
    }
}

// ---------------------------------------------------------------------------
extern "C" void kernel_launch(void* const* d_in, const int* in_sizes, int n_in,
                              void* d_out, int out_size, void* d_ws, size_t ws_size,
                              hipStream_t stream) {
    const float* nodes = (const float*)d_in[0];
    const float* ph    = (const float*)d_in[1];
    const float* gr    = (const float*)d_in[2];
    const int*   src   = (const int*)d_in[3];
    const int*   dst   = (const int*)d_in[4];
    const float* keyW  = (const float*)d_in[5];
    const float* keyb  = (const float*)d_in[6];
    const float* valW  = (const float*)d_in[7];
    const float* valb  = (const float*)d_in[8];
    const float* qW    = (const float*)d_in[9];
    const float* qb    = (const float*)d_in[10];
    const float* Wih   = (const float*)d_in[11];
    const float* Whh   = (const float*)d_in[12];
    const float* bih   = (const float*)d_in[13];
    const float* bhh   = (const float*)d_in[14];
    const float* lng   = (const float*)d_in[15];
    const float* lnb   = (const float*)d_in[16];
    const float* W1    = (const float*)d_in[17];
    const float* b1    = (const float*)d_in[18];
    const float* W2    = (const float*)d_in[19];
    const float* b2    = (const float*)d_in[20];
    float* out = (float*)d_out;

    // workspace layout
    float* ws_f      = (float*)d_ws;
    float* qk        = ws_f;                     // 640,000
    float* qoff      = qk + 640000;              // 5,008
    float* agg       = qoff + 5008;              // 640,000
    float* att_sum   = agg + 640000;             // 5,008
    int*   totals    = (int*)(att_sum + 5008);   // 5,008
    int*   offsets   = totals + 5008;            // 5,008
    int*   blockhist = offsets + 5008;           // NBLK*5000
    int*   ssrc      = blockhist + (size_t)NBLK * N_PART;  // 1,000,000
    float* Wbig      = (float*)(ssrc + 1000000); // 131,072
    float* bvec      = Wbig + 131072;            // 384 (+pad)

    build_wbig_kernel<<<512, 256, 0, stream>>>(valW, Wih, Whh, Wbig);
    build_bvec_kernel<<<2, 256, 0, stream>>>(valb, Wih, bvec);
    query_qk_kernel<<<N_PART, 128, 0, stream>>>(ph, gr, qW, qb, keyW, keyb, qk, qoff);
    block_hist_kernel<<<NBLK, 256, 0, stream>>>(dst, blockhist);
    colscan_kernel<<<(N_PART + 255) / 256, 256, 0, stream>>>(blockhist, totals);
    scan_kernel<<<1, 256, 0, stream>>>(totals, offsets);
    scatter_sorted_kernel<<<NBLK, 256, 0, stream>>>(src, dst, offsets, blockhist, ssrc);
    edge_agg_kernel<<<N_PART, 256, 0, stream>>>(nodes, qk, qoff, offsets, ssrc, agg, att_sum);
    gru_fused_v4<<<N_PART / TPV3, 256, 0, stream>>>(
        agg, att_sum, ph, Wbig, bvec, bih, bhh, lng, lnb, W1, b1, W2, b2, out);
}

// Round 3
// 326.647 us; speedup vs baseline: 1.0535x; 1.0235x over previous
//
#include <hip/hip_runtime.h>
#include <math.h>

#define N_NODES 100000
#define N_PART  5000
#define N_EDGES 1000000
#define D_NODE  128
#define D_PART  128
#define D_ATT   20
#define NBLK    128   // counting-sort blocks
#define EPB     ((N_EDGES + NBLK - 1) / NBLK)
#define TPV3    10    // particles per block in gru_fused_v5 (5000 = 500*10)

__device__ __forceinline__ float sigmoid_(float x) { return 1.f / (1.f + __expf(-x)); }
__device__ __forceinline__ float tanh_(float x)    { return 1.f - 2.f / (__expf(2.f * x) + 1.f); }

// ---------------------------------------------------------------------------
// P0: build combined GRU weight matrix Wbig[256][512], GATE-INTERLEAVED:
//   new column jn = c*4 + g  (c in [0,128), g in {0:r, 1:z, 2:i_n, 3:h_n})
//   maps to old column j = g*128 + c with old semantics:
//   rows 0..127  (agg side k):  old j<384: sum_m valW[k][m]*Wih[j][m]; else 0
//   rows 128..255 (h side k'):  old j<256: Whh[j][k']; 256..383: 0;
//                               >=384: Whh[j-128][k']
// ---------------------------------------------------------------------------
__global__ __launch_bounds__(256) void build_wbig_kernel(
    const float* __restrict__ valW, const float* __restrict__ Wih,
    const float* __restrict__ Whh, float* __restrict__ Wbig)
{
    int idx = blockIdx.x * 256 + threadIdx.x;   // 131072 total
    int k = idx >> 9;
    int jn = idx & 511;
    int j = (jn & 3) * 128 + (jn >> 2);         // old column
    float v = 0.f;
    if (k < 128) {
        if (j < 384) {
            float acc = 0.f;
            #pragma unroll 8
            for (int m = 0; m < 128; m++)
                acc += valW[k * 128 + m] * Wih[j * 128 + m];
            v = acc;
        }
    } else {
        int kp = k - 128;
        if (j < 256)       v = Whh[j * 128 + kp];
        else if (j >= 384) v = Whh[(j - 128) * 128 + kp];
    }
    Wbig[k * 512 + jn] = v;
}

// P0b: bvec[c] = sum_m valb[m] * Wih[c][m],  c < 384  (old column indexing)
__global__ __launch_bounds__(256) void build_bvec_kernel(
    const float* __restrict__ valb, const float* __restrict__ Wih,
    float* __restrict__ bvec)
{
    int c = blockIdx.x * 256 + threadIdx.x;
    if (c < 384) {
        float acc = 0.f;
        #pragma unroll 8
        for (int m = 0; m < 128; m++) acc += valb[m] * Wih[c * 128 + m];
        bvec[c] = acc;
    }
}

// ---------------------------------------------------------------------------
// K1: query = [ph|gr] @ q_W + q_b, fold key_W/key_b:
//     qk[p][j] = sum_a key_W[j][a]*query[p][a];  qoff[p] = key_b . query[p]
// ---------------------------------------------------------------------------
__global__ __launch_bounds__(128) void query_qk_kernel(
    const float* __restrict__ ph, const float* __restrict__ gr,
    const float* __restrict__ qW, const float* __restrict__ qb,
    const float* __restrict__ keyW, const float* __restrict__ keyb,
    float* __restrict__ qk, float* __restrict__ qoff)
{
    int p = blockIdx.x;
    int t = threadIdx.x;
    __shared__ float s_in[256];
    __shared__ float s_q[D_ATT];

    s_in[t]       = ph[p * 128 + t];
    s_in[128 + t] = gr[p * 128 + t];
    __syncthreads();

    if (t < D_ATT) {
        float acc = qb[t];
        #pragma unroll 8
        for (int k = 0; k < 256; k++) acc += s_in[k] * qW[k * D_ATT + t];
        s_q[t] = acc;
    }
    __syncthreads();

    float acc = 0.f;
    #pragma unroll
    for (int a = 0; a < D_ATT; a++) acc += keyW[t * D_ATT + a] * s_q[a];
    qk[p * 128 + t] = acc;

    if (t == 0) {
        float o = 0.f;
        #pragma unroll
        for (int a = 0; a < D_ATT; a++) o += keyb[a] * s_q[a];
        qoff[p] = o;
    }
}

// ---------------------------------------------------------------------------
// K2a: per-block LDS histogram of dst
// ---------------------------------------------------------------------------
__global__ __launch_bounds__(256) void block_hist_kernel(
    const int* __restrict__ dst, int* __restrict__ blockhist)
{
    __shared__ int h[N_PART];
    int b = blockIdx.x;
    for (int i = threadIdx.x; i < N_PART; i += 256) h[i] = 0;
    __syncthreads();
    int beg = b * EPB, end = min(beg + EPB, N_EDGES);
    for (int e = beg + threadIdx.x; e < end; e += 256)
        atomicAdd(&h[dst[e]], 1);
    __syncthreads();
    for (int i = threadIdx.x; i < N_PART; i += 256)
        blockhist[(size_t)b * N_PART + i] = h[i];
}

// ---------------------------------------------------------------------------
// K2b: per-dst column scan over blocks
// ---------------------------------------------------------------------------
__global__ __launch_bounds__(256) void colscan_kernel(
    int* __restrict__ blockhist, int* __restrict__ totals)
{
    int i = blockIdx.x * 256 + threadIdx.x;
    if (i >= N_PART) return;
    int run = 0;
    for (int b = 0; b < NBLK; b++) {
        size_t idx = (size_t)b * N_PART + i;
        int v = blockhist[idx];
        blockhist[idx] = run;
        run += v;
    }
    totals[i] = run;
}

// ---------------------------------------------------------------------------
// K2c: exclusive scan of totals[5000] -> offsets[5001]
// ---------------------------------------------------------------------------
__global__ __launch_bounds__(256) void scan_kernel(
    const int* __restrict__ totals, int* __restrict__ offsets)
{
    __shared__ int ss[256];
    int t = threadIdx.x;
    const int CH = 20;
    int beg = t * CH;
    int end = min(beg + CH, N_PART);
    int lsum = 0;
    for (int i = beg; i < end; i++) lsum += totals[i];
    ss[t] = lsum;
    __syncthreads();
    for (int off = 1; off < 256; off <<= 1) {
        int v = (t >= off) ? ss[t - off] : 0;
        __syncthreads();
        ss[t] += v;
        __syncthreads();
    }
    int base = ss[t] - lsum;
    for (int i = beg; i < end; i++) {
        offsets[i] = base;
        base += totals[i];
    }
    if (t == 0) offsets[N_PART] = N_EDGES;
}

// ---------------------------------------------------------------------------
// K2d: scatter src into dst-sorted order using per-block LDS cursors
// ---------------------------------------------------------------------------
__global__ __launch_bounds__(256) void scatter_sorted_kernel(
    const int* __restrict__ src, const int* __restrict__ dst,
    const int* __restrict__ offsets, const int* __restrict__ blockhist,
    int* __restrict__ ssrc)
{
    __shared__ int cur[N_PART];
    int b = blockIdx.x;
    for (int i = threadIdx.x; i < N_PART; i += 256)
        cur[i] = offsets[i] + blockhist[(size_t)b * N_PART + i];
    __syncthreads();
    int beg = b * EPB, end = min(beg + EPB, N_EDGES);
    for (int e = beg + threadIdx.x; e < end; e += 256) {
        int d = dst[e];
        int pos = atomicAdd(&cur[d], 1);
        ssrc[pos] = src[e];
    }
}

// ---------------------------------------------------------------------------
// K3: per-dst edge accumulation. Half-wave (32 lanes x float4) per edge.
// Round-0 form (known-good, at gather-service ceiling per round-1 A/B).
// ---------------------------------------------------------------------------
__global__ __launch_bounds__(256) void edge_agg_kernel(
    const float* __restrict__ nodes, const float* __restrict__ qk,
    const float* __restrict__ qoff,
    const int* __restrict__ offsets, const int* __restrict__ ssrc,
    float* __restrict__ agg, float* __restrict__ att_sum)
{
    const float norm = 0.22360679774997896f;  // 1/sqrt(20)
    int p = blockIdx.x;
    int tid = threadIdx.x;
    int lane = tid & 63;
    int wave = tid >> 6;
    int half = lane >> 5;
    int colq = (lane & 31) * 4;

    const float4 q = *(const float4*)(qk + (size_t)p * 128 + colq);
    float qo = qoff[p];
    int beg = offsets[p], end = offsets[p + 1];
    int n = end - beg;
    int np = (n + 1) >> 1;   // total pairs (last may be partial)
    int npfull = n >> 1;     // pairs with both edges present

    float4 a = {0.f, 0.f, 0.f, 0.f};
    float asum = 0.f;

    int pi = wave;
    // main loop: 4 full pairs pi, pi+4, pi+8, pi+12
    for (; pi + 12 < npfull; pi += 16) {
        int e0 = beg + 2 * pi + half;
        int s0 = ssrc[e0];
        int s1 = ssrc[e0 + 8];
        int s2 = ssrc[e0 + 16];
        int s3 = ssrc[e0 + 24];
        float4 x0 = *(const float4*)(nodes + (size_t)s0 * 128 + colq);
        float4 x1 = *(const float4*)(nodes + (size_t)s1 * 128 + colq);
        float4 x2 = *(const float4*)(nodes + (size_t)s2 * 128 + colq);
        float4 x3 = *(const float4*)(nodes + (size_t)s3 * 128 + colq);
        float d0 = x0.x * q.x + x0.y * q.y + x0.z * q.z + x0.w * q.w;
        float d1 = x1.x * q.x + x1.y * q.y + x1.z * q.z + x1.w * q.w;
        float d2 = x2.x * q.x + x2.y * q.y + x2.z * q.z + x2.w * q.w;
        float d3 = x3.x * q.x + x3.y * q.y + x3.z * q.z + x3.w * q.w;
        #pragma unroll
        for (int off = 1; off <= 16; off <<= 1) {
            d0 += __shfl_xor(d0, off, 64);
            d1 += __shfl_xor(d1, off, 64);
            d2 += __shfl_xor(d2, off, 64);
            d3 += __shfl_xor(d3, off, 64);
        }
        float t0 = (d0 + qo) * norm;
        float t1 = (d1 + qo) * norm;
        float t2 = (d2 + qo) * norm;
        float t3 = (d3 + qo) * norm;
        a.x += t0 * x0.x + t1 * x1.x + t2 * x2.x + t3 * x3.x;
        a.y += t0 * x0.y + t1 * x1.y + t2 * x2.y + t3 * x3.y;
        a.z += t0 * x0.z + t1 * x1.z + t2 * x2.z + t3 * x3.z;
        a.w += t0 * x0.w + t1 * x1.w + t2 * x2.w + t3 * x3.w;
        asum += t0 + t1 + t2 + t3;
    }
    // remainder: guarded single pairs
    for (; pi < np; pi += 4) {
        int e0 = beg + 2 * pi;
        bool has1 = (e0 + 1 < end);
        int s0 = ssrc[e0];
        int s1 = has1 ? ssrc[e0 + 1] : s0;
        int s = half ? s1 : s0;
        float4 x = *(const float4*)(nodes + (size_t)s * 128 + colq);
        float d = x.x * q.x + x.y * q.y + x.z * q.z + x.w * q.w;
        #pragma unroll
        for (int off = 1; off <= 16; off <<= 1) d += __shfl_xor(d, off, 64);
        float att = (d + qo) * norm;
        if (half && !has1) att = 0.f;
        a.x += att * x.x; a.y += att * x.y; a.z += att * x.z; a.w += att * x.w;
        asum += att;
    }

    a.x += __shfl_xor(a.x, 32, 64);
    a.y += __shfl_xor(a.y, 32, 64);
    a.z += __shfl_xor(a.z, 32, 64);
    a.w += __shfl_xor(a.w, 32, 64);
    asum += __shfl_xor(asum, 32, 64);

    __shared__ float s_acc[4][128];
    __shared__ float s_as[4];
    if (lane < 32) {
        *(float4*)&s_acc[wave][colq] = a;
        if (lane == 0) s_as[wave] = asum;
    }
    __syncthreads();

    if (tid < 128) {
        float v = s_acc[0][tid] + s_acc[1][tid] + s_acc[2][tid] + s_acc[3][tid];
        agg[(size_t)p * 128 + tid] = v;
        if (tid == 0) att_sum[p] = s_as[0] + s_as[1] + s_as[2] + s_as[3];
    }
}

// ---------------------------------------------------------------------------
// K4 v5: single K=256 GEMM  G = [agg|h] @ Wbig_interleaved (+bias/asum*bvec),
// gates in registers + LayerNorm + MLP + residual, one kernel.
// v5: NO LDS staging of Wbig, NO K-loop barriers. w is read directly from
// global (Wbig is 512KB -> L2-resident; coalesced 1KB/wave dwordx4 loads,
// 4 in flight per wave). LDS carries only s_in/s_ln/s_hid (~18KB).
// x-broadcasts vectorized: 5 ds_read_b128 per 4-k body (vs 20 b32).
// DS pipe and VMEM pipe now overlap freely across waves (no barrier drains).
// ---------------------------------------------------------------------------
__global__ __launch_bounds__(256) void gru_fused_v5(
    const float* __restrict__ agg, const float* __restrict__ att_sum,
    const float* __restrict__ ph,
    const float* __restrict__ Wbig, const float* __restrict__ bvec,
    const float* __restrict__ bih, const float* __restrict__ bhh,
    const float* __restrict__ lng, const float* __restrict__ lnb,
    const float* __restrict__ W1, const float* __restrict__ b1,
    const float* __restrict__ W2, const float* __restrict__ b2,
    float* __restrict__ out)
{
    __shared__ float s_in[TPV3][256];    // [agg | h] per particle (10240 B)
    __shared__ float s_ln[TPV3][128];    //                        (5120 B)
    __shared__ float s_hid[TPV3][64];    //                        (2560 B)

    int t = threadIdx.x;
    int pbase = blockIdx.x * TPV3;

    // ---- load inputs: 10 particles x 256 floats = 640 float4 jobs
    for (int f = t; f < TPV3 * 64; f += 256) {
        int pl = f >> 6, r = f & 63;
        int c4 = r * 4;
        int p = pbase + pl;
        float4 v;
        if (c4 < 128) v = *(const float4*)(agg + (size_t)p * 128 + c4);
        else          v = *(const float4*)(ph + (size_t)p * 128 + (c4 - 128));
        *(float4*)&s_in[pl][c4] = v;
    }

    // ---- accumulator init: bias + asum * bvec (gate-interleaved)
    int c  = t & 127;        // output column 0..127
    int j4 = c * 4;          // interleaved column base in Wbig
    int pg = t >> 7;         // particle group 0/1 -> particles pg*5 .. pg*5+4
    float4 cb, bv;
    cb.x = bih[c]       + bhh[c];        bv.x = bvec[c];        // r
    cb.y = bih[128 + c] + bhh[128 + c];  bv.y = bvec[128 + c];  // z
    cb.z = bih[256 + c];                 bv.z = bvec[256 + c];  // i_n
    cb.w = bhh[256 + c];                 bv.w = 0.f;            // h_n
    float4 acc[5];
    #pragma unroll
    for (int i = 0; i < 5; i++) {
        float as = att_sum[pbase + pg * 5 + i];
        acc[i].x = cb.x + as * bv.x;
        acc[i].y = cb.y + as * bv.y;
        acc[i].z = cb.z + as * bv.z;
        acc[i].w = cb.w + as * bv.w;
    }
    __syncthreads();

    // ---- K-loop: barrier-free, w direct from L2-resident global.
    // Per body (4 k): 4 global dwordx4 (w rows) + 5 ds_read_b128 (x quads).
    const float* wp = Wbig + j4;
    for (int k = 0; k < 256; k += 4) {
        float4 w0 = *(const float4*)(wp + (size_t)(k    ) * 512);
        float4 w1 = *(const float4*)(wp + (size_t)(k + 1) * 512);
        float4 w2 = *(const float4*)(wp + (size_t)(k + 2) * 512);
        float4 w3 = *(const float4*)(wp + (size_t)(k + 3) * 512);
        #pragma unroll
        for (int i = 0; i < 5; i++) {
            float4 x4 = *(const float4*)&s_in[pg * 5 + i][k];
            acc[i].x += x4.x * w0.x + x4.y * w1.x + x4.z * w2.x + x4.w * w3.x;
            acc[i].y += x4.x * w0.y + x4.y * w1.y + x4.z * w2.y + x4.w * w3.y;
            acc[i].z += x4.x * w0.z + x4.y * w1.z + x4.z * w2.z + x4.w * w3.z;
            acc[i].w += x4.x * w0.w + x4.y * w1.w + x4.z * w2.w + x4.w * w3.w;
        }
    }

    // ---- gates entirely in registers: hn = (1-z)*n + z*h
    #pragma unroll
    for (int i = 0; i < 5; i++) {
        int pl = pg * 5 + i;
        float r = sigmoid_(acc[i].x);
        float z = sigmoid_(acc[i].y);
        float n = tanh_(acc[i].z + r * acc[i].w);
        float h = s_in[pl][128 + c];
        s_ln[pl][c] = (1.f - z) * n + z * h;
    }
    __syncthreads();

    // ---- LayerNorm per particle (wave w handles particles w, w+4, w+8)
    {
        int wv = t >> 6, l = t & 63;
        for (int pl = wv; pl < TPV3; pl += 4) {
            float v0 = s_ln[pl][l * 2], v1 = s_ln[pl][l * 2 + 1];
            float sum = v0 + v1, sq = v0 * v0 + v1 * v1;
            #pragma unroll
            for (int off = 1; off <= 32; off <<= 1) {
                sum += __shfl_xor(sum, off, 64);
                sq  += __shfl_xor(sq, off, 64);
            }
            float mu = sum * (1.f / 128.f);
            float var = sq * (1.f / 128.f) - mu * mu;
            float rstd = rsqrtf(var + 1e-5f);
            s_ln[pl][l * 2]     = (v0 - mu) * rstd * lng[l * 2] + lnb[l * 2];
            s_ln[pl][l * 2 + 1] = (v1 - mu) * rstd * lng[l * 2 + 1] + lnb[l * 2 + 1];
        }
    }
    __syncthreads();

    // ---- MLP hidden (10*64 = 640 outputs)
    for (int idx = t; idx < TPV3 * 64; idx += 256) {
        int pl = idx >> 6, u = idx & 63;
        float a0 = b1[u];
        #pragma unroll 4
        for (int k = 0; k < 128; k++) a0 += s_ln[pl][k] * W1[k * 64 + u];
        s_hid[pl][u] = fmaxf(a0, 0.f);
    }
    __syncthreads();

    // ---- MLP out + residual (320 column-quads)
    for (int idx = t; idx < TPV3 * 32; idx += 256) {
        int pl = idx >> 5, qd = idx & 31;
        int c4 = qd * 4;
        float4 o = *(const float4*)(b2 + c4);
        #pragma unroll 4
        for (int u = 0; u < 64; u++) {
            float av = s_hid[pl][u];
            float4 w = *(const float4*)(W2 + u * 128 + c4);
            o.x += av * w.x; o.y += av * w.y; o.z += av * w.z; o.w += av * w.w;
        }
        float4 h4 = *(const float4*)&s_in[pl][128 + c4];
        float4 res;
        res.x = h4.x + o.x; res.y = h4.y + o.y;
        res.z = h4.z + o.z; res.w = h4.w + o.w;
        *(float4*)(out + (size_t)(pbase + pl) * 128 + c4) = res;
    }
}

// ---------------------------------------------------------------------------
extern "C" void kernel_launch(void* const* d_in, const int* in_sizes, int n_in,
                              void* d_out, int out_size, void* d_ws, size_t ws_size,
                              hipStream_t stream) {
    const float* nodes = (const float*)d_in[0];
    const float* ph    = (const float*)d_in[1];
    const float* gr    = (const float*)d_in[2];
    const int*   src   = (const int*)d_in[3];
    const int*   dst   = (const int*)d_in[4];
    const float* keyW  = (const float*)d_in[5];
    const float* keyb  = (const float*)d_in[6];
    const float* valW  = (const float*)d_in[7];
    const float* valb  = (const float*)d_in[8];
    const float* qW    = (const float*)d_in[9];
    const float* qb    = (const float*)d_in[10];
    const float* Wih   = (const float*)d_in[11];
    const float* Whh   = (const float*)d_in[12];
    const float* bih   = (const float*)d_in[13];
    const float* bhh   = (const float*)d_in[14];
    const float* lng   = (const float*)d_in[15];
    const float* lnb   = (const float*)d_in[16];
    const float* W1    = (const float*)d_in[17];
    const float* b1    = (const float*)d_in[18];
    const float* W2    = (const float*)d_in[19];
    const float* b2    = (const float*)d_in[20];
    float* out = (float*)d_out;

    // workspace layout
    float* ws_f      = (float*)d_ws;
    float* qk        = ws_f;                     // 640,000
    float* qoff      = qk + 640000;              // 5,008
    float* agg       = qoff + 5008;              // 640,000
    float* att_sum   = agg + 640000;             // 5,008
    int*   totals    = (int*)(att_sum + 5008);   // 5,008
    int*   offsets   = totals + 5008;            // 5,008
    int*   blockhist = offsets + 5008;           // NBLK*5000
    int*   ssrc      = blockhist + (size_t)NBLK * N_PART;  // 1,000,000
    float* Wbig      = (float*)(ssrc + 1000000); // 131,072
    float* bvec      = Wbig + 131072;            // 384 (+pad)

    build_wbig_kernel<<<512, 256, 0, stream>>>(valW, Wih, Whh, Wbig);
    build_bvec_kernel<<<2, 256, 0, stream>>>(valb, Wih, bvec);
    query_qk_kernel<<<N_PART, 128, 0, stream>>>(ph, gr, qW, qb, keyW, keyb, qk, qoff);
    block_hist_kernel<<<NBLK, 256, 0, stream>>>(dst, blockhist);
    colscan_kernel<<<(N_PART + 255) / 256, 256, 0, stream>>>(blockhist, totals);
    scan_kernel<<<1, 256, 0, stream>>>(totals, offsets);
    scatter_sorted_kernel<<<NBLK, 256, 0, stream>>>(src, dst, offsets, blockhist, ssrc);
    edge_agg_kernel<<<N_PART, 256, 0, stream>>>(nodes, qk, qoff, offsets, ssrc, agg, att_sum);
    gru_fused_v5<<<N_PART / TPV3, 256, 0, stream>>>(
        agg, att_sum, ph, Wbig, bvec, bih, bhh, lng, lnb, W1, b1, W2, b2, out);
}

// Round 4
// 307.259 us; speedup vs baseline: 1.1200x; 1.0631x over previous
//
#include <hip/hip_runtime.h>
#include <math.h>

#define N_NODES 100000
#define N_PART  5000
#define N_EDGES 1000000
#define D_NODE  128
#define D_PART  128
#define D_ATT   20
#define NBLK    128   // counting-sort blocks
#define EPB     ((N_EDGES + NBLK - 1) / NBLK)
#define TPV6    8     // particles per block in gru_fused_v6 (5000 = 625*8)

__device__ __forceinline__ float sigmoid_(float x) { return 1.f / (1.f + __expf(-x)); }
__device__ __forceinline__ float tanh_(float x)    { return 1.f - 2.f / (__expf(2.f * x) + 1.f); }

// ---------------------------------------------------------------------------
// P0: build combined GRU weight matrix Wbig[256][512], GATE-INTERLEAVED:
//   new column jn = c*4 + g  (c in [0,128), g in {0:r, 1:z, 2:i_n, 3:h_n})
//   maps to old column j = g*128 + c with old semantics:
//   rows 0..127  (agg side k):  old j<384: sum_m valW[k][m]*Wih[j][m]; else 0
//   rows 128..255 (h side k'):  old j<256: Whh[j][k']; 256..383: 0;
//                               >=384: Whh[j-128][k']
// ---------------------------------------------------------------------------
__global__ __launch_bounds__(256) void build_wbig_kernel(
    const float* __restrict__ valW, const float* __restrict__ Wih,
    const float* __restrict__ Whh, float* __restrict__ Wbig)
{
    int idx = blockIdx.x * 256 + threadIdx.x;   // 131072 total
    int k = idx >> 9;
    int jn = idx & 511;
    int j = (jn & 3) * 128 + (jn >> 2);         // old column
    float v = 0.f;
    if (k < 128) {
        if (j < 384) {
            float acc = 0.f;
            #pragma unroll 8
            for (int m = 0; m < 128; m++)
                acc += valW[k * 128 + m] * Wih[j * 128 + m];
            v = acc;
        }
    } else {
        int kp = k - 128;
        if (j < 256)       v = Whh[j * 128 + kp];
        else if (j >= 384) v = Whh[(j - 128) * 128 + kp];
    }
    Wbig[k * 512 + jn] = v;
}

// P0b: bvec[c] = sum_m valb[m] * Wih[c][m],  c < 384  (old column indexing)
__global__ __launch_bounds__(256) void build_bvec_kernel(
    const float* __restrict__ valb, const float* __restrict__ Wih,
    float* __restrict__ bvec)
{
    int c = blockIdx.x * 256 + threadIdx.x;
    if (c < 384) {
        float acc = 0.f;
        #pragma unroll 8
        for (int m = 0; m < 128; m++) acc += valb[m] * Wih[c * 128 + m];
        bvec[c] = acc;
    }
}

// ---------------------------------------------------------------------------
// K1: query = [ph|gr] @ q_W + q_b, fold key_W/key_b:
//     qk[p][j] = sum_a key_W[j][a]*query[p][a];  qoff[p] = key_b . query[p]
// ---------------------------------------------------------------------------
__global__ __launch_bounds__(128) void query_qk_kernel(
    const float* __restrict__ ph, const float* __restrict__ gr,
    const float* __restrict__ qW, const float* __restrict__ qb,
    const float* __restrict__ keyW, const float* __restrict__ keyb,
    float* __restrict__ qk, float* __restrict__ qoff)
{
    int p = blockIdx.x;
    int t = threadIdx.x;
    __shared__ float s_in[256];
    __shared__ float s_q[D_ATT];

    s_in[t]       = ph[p * 128 + t];
    s_in[128 + t] = gr[p * 128 + t];
    __syncthreads();

    if (t < D_ATT) {
        float acc = qb[t];
        #pragma unroll 8
        for (int k = 0; k < 256; k++) acc += s_in[k] * qW[k * D_ATT + t];
        s_q[t] = acc;
    }
    __syncthreads();

    float acc = 0.f;
    #pragma unroll
    for (int a = 0; a < D_ATT; a++) acc += keyW[t * D_ATT + a] * s_q[a];
    qk[p * 128 + t] = acc;

    if (t == 0) {
        float o = 0.f;
        #pragma unroll
        for (int a = 0; a < D_ATT; a++) o += keyb[a] * s_q[a];
        qoff[p] = o;
    }
}

// ---------------------------------------------------------------------------
// K2a: per-block LDS histogram of dst
// ---------------------------------------------------------------------------
__global__ __launch_bounds__(256) void block_hist_kernel(
    const int* __restrict__ dst, int* __restrict__ blockhist)
{
    __shared__ int h[N_PART];
    int b = blockIdx.x;
    for (int i = threadIdx.x; i < N_PART; i += 256) h[i] = 0;
    __syncthreads();
    int beg = b * EPB, end = min(beg + EPB, N_EDGES);
    for (int e = beg + threadIdx.x; e < end; e += 256)
        atomicAdd(&h[dst[e]], 1);
    __syncthreads();
    for (int i = threadIdx.x; i < N_PART; i += 256)
        blockhist[(size_t)b * N_PART + i] = h[i];
}

// ---------------------------------------------------------------------------
// K2b: per-dst column scan over blocks
// ---------------------------------------------------------------------------
__global__ __launch_bounds__(256) void colscan_kernel(
    int* __restrict__ blockhist, int* __restrict__ totals)
{
    int i = blockIdx.x * 256 + threadIdx.x;
    if (i >= N_PART) return;
    int run = 0;
    for (int b = 0; b < NBLK; b++) {
        size_t idx = (size_t)b * N_PART + i;
        int v = blockhist[idx];
        blockhist[idx] = run;
        run += v;
    }
    totals[i] = run;
}

// ---------------------------------------------------------------------------
// K2c: exclusive scan of totals[5000] -> offsets[5001]
// ---------------------------------------------------------------------------
__global__ __launch_bounds__(256) void scan_kernel(
    const int* __restrict__ totals, int* __restrict__ offsets)
{
    __shared__ int ss[256];
    int t = threadIdx.x;
    const int CH = 20;
    int beg = t * CH;
    int end = min(beg + CH, N_PART);
    int lsum = 0;
    for (int i = beg; i < end; i++) lsum += totals[i];
    ss[t] = lsum;
    __syncthreads();
    for (int off = 1; off < 256; off <<= 1) {
        int v = (t >= off) ? ss[t - off] : 0;
        __syncthreads();
        ss[t] += v;
        __syncthreads();
    }
    int base = ss[t] - lsum;
    for (int i = beg; i < end; i++) {
        offsets[i] = base;
        base += totals[i];
    }
    if (t == 0) offsets[N_PART] = N_EDGES;
}

// ---------------------------------------------------------------------------
// K2d: scatter src into dst-sorted order using per-block LDS cursors
// ---------------------------------------------------------------------------
__global__ __launch_bounds__(256) void scatter_sorted_kernel(
    const int* __restrict__ src, const int* __restrict__ dst,
    const int* __restrict__ offsets, const int* __restrict__ blockhist,
    int* __restrict__ ssrc)
{
    __shared__ int cur[N_PART];
    int b = blockIdx.x;
    for (int i = threadIdx.x; i < N_PART; i += 256)
        cur[i] = offsets[i] + blockhist[(size_t)b * N_PART + i];
    __syncthreads();
    int beg = b * EPB, end = min(beg + EPB, N_EDGES);
    for (int e = beg + threadIdx.x; e < end; e += 256) {
        int d = dst[e];
        int pos = atomicAdd(&cur[d], 1);
        ssrc[pos] = src[e];
    }
}

// ---------------------------------------------------------------------------
// K3: per-dst edge accumulation. Half-wave (32 lanes x float4) per edge.
// Round-0 form (known-good, at gather-service ceiling per round-1 A/B).
// ---------------------------------------------------------------------------
__global__ __launch_bounds__(256) void edge_agg_kernel(
    const float* __restrict__ nodes, const float* __restrict__ qk,
    const float* __restrict__ qoff,
    const int* __restrict__ offsets, const int* __restrict__ ssrc,
    float* __restrict__ agg, float* __restrict__ att_sum)
{
    const float norm = 0.22360679774997896f;  // 1/sqrt(20)
    int p = blockIdx.x;
    int tid = threadIdx.x;
    int lane = tid & 63;
    int wave = tid >> 6;
    int half = lane >> 5;
    int colq = (lane & 31) * 4;

    const float4 q = *(const float4*)(qk + (size_t)p * 128 + colq);
    float qo = qoff[p];
    int beg = offsets[p], end = offsets[p + 1];
    int n = end - beg;
    int np = (n + 1) >> 1;   // total pairs (last may be partial)
    int npfull = n >> 1;     // pairs with both edges present

    float4 a = {0.f, 0.f, 0.f, 0.f};
    float asum = 0.f;

    int pi = wave;
    // main loop: 4 full pairs pi, pi+4, pi+8, pi+12
    for (; pi + 12 < npfull; pi += 16) {
        int e0 = beg + 2 * pi + half;
        int s0 = ssrc[e0];
        int s1 = ssrc[e0 + 8];
        int s2 = ssrc[e0 + 16];
        int s3 = ssrc[e0 + 24];
        float4 x0 = *(const float4*)(nodes + (size_t)s0 * 128 + colq);
        float4 x1 = *(const float4*)(nodes + (size_t)s1 * 128 + colq);
        float4 x2 = *(const float4*)(nodes + (size_t)s2 * 128 + colq);
        float4 x3 = *(const float4*)(nodes + (size_t)s3 * 128 + colq);
        float d0 = x0.x * q.x + x0.y * q.y + x0.z * q.z + x0.w * q.w;
        float d1 = x1.x * q.x + x1.y * q.y + x1.z * q.z + x1.w * q.w;
        float d2 = x2.x * q.x + x2.y * q.y + x2.z * q.z + x2.w * q.w;
        float d3 = x3.x * q.x + x3.y * q.y + x3.z * q.z + x3.w * q.w;
        #pragma unroll
        for (int off = 1; off <= 16; off <<= 1) {
            d0 += __shfl_xor(d0, off, 64);
            d1 += __shfl_xor(d1, off, 64);
            d2 += __shfl_xor(d2, off, 64);
            d3 += __shfl_xor(d3, off, 64);
        }
        float t0 = (d0 + qo) * norm;
        float t1 = (d1 + qo) * norm;
        float t2 = (d2 + qo) * norm;
        float t3 = (d3 + qo) * norm;
        a.x += t0 * x0.x + t1 * x1.x + t2 * x2.x + t3 * x3.x;
        a.y += t0 * x0.y + t1 * x1.y + t2 * x2.y + t3 * x3.y;
        a.z += t0 * x0.z + t1 * x1.z + t2 * x2.z + t3 * x3.z;
        a.w += t0 * x0.w + t1 * x1.w + t2 * x2.w + t3 * x3.w;
        asum += t0 + t1 + t2 + t3;
    }
    // remainder: guarded single pairs
    for (; pi < np; pi += 4) {
        int e0 = beg + 2 * pi;
        bool has1 = (e0 + 1 < end);
        int s0 = ssrc[e0];
        int s1 = has1 ? ssrc[e0 + 1] : s0;
        int s = half ? s1 : s0;
        float4 x = *(const float4*)(nodes + (size_t)s * 128 + colq);
        float d = x.x * q.x + x.y * q.y + x.z * q.z + x.w * q.w;
        #pragma unroll
        for (int off = 1; off <= 16; off <<= 1) d += __shfl_xor(d, off, 64);
        float att = (d + qo) * norm;
        if (half && !has1) att = 0.f;
        a.x += att * x.x; a.y += att * x.y; a.z += att * x.z; a.w += att * x.w;
        asum += att;
    }

    a.x += __shfl_xor(a.x, 32, 64);
    a.y += __shfl_xor(a.y, 32, 64);
    a.z += __shfl_xor(a.z, 32, 64);
    a.w += __shfl_xor(a.w, 32, 64);
    asum += __shfl_xor(asum, 32, 64);

    __shared__ float s_acc[4][128];
    __shared__ float s_as[4];
    if (lane < 32) {
        *(float4*)&s_acc[wave][colq] = a;
        if (lane == 0) s_as[wave] = asum;
    }
    __syncthreads();

    if (tid < 128) {
        float v = s_acc[0][tid] + s_acc[1][tid] + s_acc[2][tid] + s_acc[3][tid];
        agg[(size_t)p * 128 + tid] = v;
        if (tid == 0) att_sum[p] = s_as[0] + s_as[1] + s_as[2] + s_as[3];
    }
}

// ---------------------------------------------------------------------------
// K4 v6: single K=256 GEMM  G = [agg|h] @ Wbig_interleaved (+bias/asum*bvec),
// gates in registers + LayerNorm + MLP + residual, one kernel.
// v6 vs v5 (v5 measured 72us, VALUBusy 20.7%, VGPR 40 => latency-bound,
// compiler not prefetching):
//   (a) TPV 10 -> 8: 625 blocks / 2500 waves (~2.5 waves/SIMD, +25% TLP)
//   (b) explicit 1-body software pipeline: body k+4's 4 w-rows (global/L2,
//       ~250cy) and 4 x-quads (LDS broadcast) are loaded BEFORE body k's
//       64 FMAs, so the L2 latency overlaps compute instead of serializing.
// ---------------------------------------------------------------------------
__global__ __launch_bounds__(256) void gru_fused_v6(
    const float* __restrict__ agg, const float* __restrict__ att_sum,
    const float* __restrict__ ph,
    const float* __restrict__ Wbig, const float* __restrict__ bvec,
    const float* __restrict__ bih, const float* __restrict__ bhh,
    const float* __restrict__ lng, const float* __restrict__ lnb,
    const float* __restrict__ W1, const float* __restrict__ b1,
    const float* __restrict__ W2, const float* __restrict__ b2,
    float* __restrict__ out)
{
    __shared__ float s_in[TPV6][256];    // [agg | h] per particle (8192 B)
    __shared__ float s_ln[TPV6][128];    //                        (4096 B)
    __shared__ float s_hid[TPV6][64];    //                        (2048 B)

    int t = threadIdx.x;
    int pbase = blockIdx.x * TPV6;

    // ---- load inputs: 8 particles x 256 floats = 512 float4 jobs
    for (int f = t; f < TPV6 * 64; f += 256) {
        int pl = f >> 6, r = f & 63;
        int c4 = r * 4;
        int p = pbase + pl;
        float4 v;
        if (c4 < 128) v = *(const float4*)(agg + (size_t)p * 128 + c4);
        else          v = *(const float4*)(ph + (size_t)p * 128 + (c4 - 128));
        *(float4*)&s_in[pl][c4] = v;
    }

    // ---- accumulator init: bias + asum * bvec (gate-interleaved)
    int c  = t & 127;        // output column 0..127
    int j4 = c * 4;          // interleaved column base in Wbig
    int pg = t >> 7;         // particle group 0/1 -> particles pg*4 .. pg*4+3
    float4 cb, bv;
    cb.x = bih[c]       + bhh[c];        bv.x = bvec[c];        // r
    cb.y = bih[128 + c] + bhh[128 + c];  bv.y = bvec[128 + c];  // z
    cb.z = bih[256 + c];                 bv.z = bvec[256 + c];  // i_n
    cb.w = bhh[256 + c];                 bv.w = 0.f;            // h_n
    float4 acc[4];
    #pragma unroll
    for (int i = 0; i < 4; i++) {
        float as = att_sum[pbase + pg * 4 + i];
        acc[i].x = cb.x + as * bv.x;
        acc[i].y = cb.y + as * bv.y;
        acc[i].z = cb.z + as * bv.z;
        acc[i].w = cb.w + as * bv.w;
    }
    __syncthreads();

    // ---- K-loop: barrier-free, w direct from L2-resident global,
    //      1-body-ahead register prefetch for w (global) and x (LDS).
    const float* wp = Wbig + j4;
    float4 w0 = *(const float4*)(wp);
    float4 w1 = *(const float4*)(wp + 512);
    float4 w2 = *(const float4*)(wp + 1024);
    float4 w3 = *(const float4*)(wp + 1536);
    float4 x0 = *(const float4*)&s_in[pg * 4 + 0][0];
    float4 x1 = *(const float4*)&s_in[pg * 4 + 1][0];
    float4 x2 = *(const float4*)&s_in[pg * 4 + 2][0];
    float4 x3 = *(const float4*)&s_in[pg * 4 + 3][0];
    for (int k = 0; k < 256; k += 4) {
        float4 cw0 = w0, cw1 = w1, cw2 = w2, cw3 = w3;
        float4 cx0 = x0, cx1 = x1, cx2 = x2, cx3 = x3;
        if (k < 252) {
            const float* wn = wp + (size_t)(k + 4) * 512;
            w0 = *(const float4*)(wn);
            w1 = *(const float4*)(wn + 512);
            w2 = *(const float4*)(wn + 1024);
            w3 = *(const float4*)(wn + 1536);
            x0 = *(const float4*)&s_in[pg * 4 + 0][k + 4];
            x1 = *(const float4*)&s_in[pg * 4 + 1][k + 4];
            x2 = *(const float4*)&s_in[pg * 4 + 2][k + 4];
            x3 = *(const float4*)&s_in[pg * 4 + 3][k + 4];
        }
        acc[0].x += cx0.x * cw0.x + cx0.y * cw1.x + cx0.z * cw2.x + cx0.w * cw3.x;
        acc[0].y += cx0.x * cw0.y + cx0.y * cw1.y + cx0.z * cw2.y + cx0.w * cw3.y;
        acc[0].z += cx0.x * cw0.z + cx0.y * cw1.z + cx0.z * cw2.z + cx0.w * cw3.z;
        acc[0].w += cx0.x * cw0.w + cx0.y * cw1.w + cx0.z * cw2.w + cx0.w * cw3.w;
        acc[1].x += cx1.x * cw0.x + cx1.y * cw1.x + cx1.z * cw2.x + cx1.w * cw3.x;
        acc[1].y += cx1.x * cw0.y + cx1.y * cw1.y + cx1.z * cw2.y + cx1.w * cw3.y;
        acc[1].z += cx1.x * cw0.z + cx1.y * cw1.z + cx1.z * cw2.z + cx1.w * cw3.z;
        acc[1].w += cx1.x * cw0.w + cx1.y * cw1.w + cx1.z * cw2.w + cx1.w * cw3.w;
        acc[2].x += cx2.x * cw0.x + cx2.y * cw1.x + cx2.z * cw2.x + cx2.w * cw3.x;
        acc[2].y += cx2.x * cw0.y + cx2.y * cw1.y + cx2.z * cw2.y + cx2.w * cw3.y;
        acc[2].z += cx2.x * cw0.z + cx2.y * cw1.z + cx2.z * cw2.z + cx2.w * cw3.z;
        acc[2].w += cx2.x * cw0.w + cx2.y * cw1.w + cx2.z * cw2.w + cx2.w * cw3.w;
        acc[3].x += cx3.x * cw0.x + cx3.y * cw1.x + cx3.z * cw2.x + cx3.w * cw3.x;
        acc[3].y += cx3.x * cw0.y + cx3.y * cw1.y + cx3.z * cw2.y + cx3.w * cw3.y;
        acc[3].z += cx3.x * cw0.z + cx3.y * cw1.z + cx3.z * cw2.z + cx3.w * cw3.z;
        acc[3].w += cx3.x * cw0.w + cx3.y * cw1.w + cx3.z * cw2.w + cx3.w * cw3.w;
    }

    // ---- gates entirely in registers: hn = (1-z)*n + z*h
    #pragma unroll
    for (int i = 0; i < 4; i++) {
        int pl = pg * 4 + i;
        float r = sigmoid_(acc[i].x);
        float z = sigmoid_(acc[i].y);
        float n = tanh_(acc[i].z + r * acc[i].w);
        float h = s_in[pl][128 + c];
        s_ln[pl][c] = (1.f - z) * n + z * h;
    }
    __syncthreads();

    // ---- LayerNorm per particle (wave w handles particles w, w+4)
    {
        int wv = t >> 6, l = t & 63;
        for (int pl = wv; pl < TPV6; pl += 4) {
            float v0 = s_ln[pl][l * 2], v1 = s_ln[pl][l * 2 + 1];
            float sum = v0 + v1, sq = v0 * v0 + v1 * v1;
            #pragma unroll
            for (int off = 1; off <= 32; off <<= 1) {
                sum += __shfl_xor(sum, off, 64);
                sq  += __shfl_xor(sq, off, 64);
            }
            float mu = sum * (1.f / 128.f);
            float var = sq * (1.f / 128.f) - mu * mu;
            float rstd = rsqrtf(var + 1e-5f);
            s_ln[pl][l * 2]     = (v0 - mu) * rstd * lng[l * 2] + lnb[l * 2];
            s_ln[pl][l * 2 + 1] = (v1 - mu) * rstd * lng[l * 2 + 1] + lnb[l * 2 + 1];
        }
    }
    __syncthreads();

    // ---- MLP hidden (8*64 = 512 outputs)
    for (int idx = t; idx < TPV6 * 64; idx += 256) {
        int pl = idx >> 6, u = idx & 63;
        float a0 = b1[u];
        #pragma unroll 4
        for (int k = 0; k < 128; k++) a0 += s_ln[pl][k] * W1[k * 64 + u];
        s_hid[pl][u] = fmaxf(a0, 0.f);
    }
    __syncthreads();

    // ---- MLP out + residual (256 column-quads)
    for (int idx = t; idx < TPV6 * 32; idx += 256) {
        int pl = idx >> 5, qd = idx & 31;
        int c4 = qd * 4;
        float4 o = *(const float4*)(b2 + c4);
        #pragma unroll 4
        for (int u = 0; u < 64; u++) {
            float av = s_hid[pl][u];
            float4 w = *(const float4*)(W2 + u * 128 + c4);
            o.x += av * w.x; o.y += av * w.y; o.z += av * w.z; o.w += av * w.w;
        }
        float4 h4 = *(const float4*)&s_in[pl][128 + c4];
        float4 res;
        res.x = h4.x + o.x; res.y = h4.y + o.y;
        res.z = h4.z + o.z; res.w = h4.w + o.w;
        *(float4*)(out + (size_t)(pbase + pl) * 128 + c4) = res;
    }
}

// ---------------------------------------------------------------------------
extern "C" void kernel_launch(void* const* d_in, const int* in_sizes, int n_in,
                              void* d_out, int out_size, void* d_ws, size_t ws_size,
                              hipStream_t stream) {
    const float* nodes = (const float*)d_in[0];
    const float* ph    = (const float*)d_in[1];
    const float* gr    = (const float*)d_in[2];
    const int*   src   = (const int*)d_in[3];
    const int*   dst   = (const int*)d_in[4];
    const float* keyW  = (const float*)d_in[5];
    const float* keyb  = (const float*)d_in[6];
    const float* valW  = (const float*)d_in[7];
    const float* valb  = (const float*)d_in[8];
    const float* qW    = (const float*)d_in[9];
    const float* qb    = (const float*)d_in[10];
    const float* Wih   = (const float*)d_in[11];
    const float* Whh   = (const float*)d_in[12];
    const float* bih   = (const float*)d_in[13];
    const float* bhh   = (const float*)d_in[14];
    const float* lng   = (const float*)d_in[15];
    const float* lnb   = (const float*)d_in[16];
    const float* W1    = (const float*)d_in[17];
    const float* b1    = (const float*)d_in[18];
    const float* W2    = (const float*)d_in[19];
    const float* b2    = (const float*)d_in[20];
    float* out = (float*)d_out;

    // workspace layout
    float* ws_f      = (float*)d_ws;
    float* qk        = ws_f;                     // 640,000
    float* qoff      = qk + 640000;              // 5,008
    float* agg       = qoff + 5008;              // 640,000
    float* att_sum   = agg + 640000;             // 5,008
    int*   totals    = (int*)(att_sum + 5008);   // 5,008
    int*   offsets   = totals + 5008;            // 5,008
    int*   blockhist = offsets + 5008;           // NBLK*5000
    int*   ssrc      = blockhist + (size_t)NBLK * N_PART;  // 1,000,000
    float* Wbig      = (float*)(ssrc + 1000000); // 131,072
    float* bvec      = Wbig + 131072;            // 384 (+pad)

    build_wbig_kernel<<<512, 256, 0, stream>>>(valW, Wih, Whh, Wbig);
    build_bvec_kernel<<<2, 256, 0, stream>>>(valb, Wih, bvec);
    query_qk_kernel<<<N_PART, 128, 0, stream>>>(ph, gr, qW, qb, keyW, keyb, qk, qoff);
    block_hist_kernel<<<NBLK, 256, 0, stream>>>(dst, blockhist);
    colscan_kernel<<<(N_PART + 255) / 256, 256, 0, stream>>>(blockhist, totals);
    scan_kernel<<<1, 256, 0, stream>>>(totals, offsets);
    scatter_sorted_kernel<<<NBLK, 256, 0, stream>>>(src, dst, offsets, blockhist, ssrc);
    edge_agg_kernel<<<N_PART, 256, 0, stream>>>(nodes, qk, qoff, offsets, ssrc, agg, att_sum);
    gru_fused_v6<<<N_PART / TPV6, 256, 0, stream>>>(
        agg, att_sum, ph, Wbig, bvec, bih, bhh, lng, lnb, W1, b1, W2, b2, out);
}